// Round 7
// baseline (367.515 us; speedup 1.0000x reference)
//
#include <hip/hip_runtime.h>
#include <hip/hip_bf16.h>
#include <math.h>

#define NBATCH 8
#define NC 256
#define ND 32
#define SN 4096

// Workspace byte offsets
constexpr size_t VB_B   = 0;                      // 16 MB bf16 V [b][o][n]
constexpr size_t QT_B   = 16777216;               // 2 MB bf16 Q^T [b][n][d] (pre-scaled by log2e)
constexpr size_t KT_B   = QT_B + 2097152;         // 2 MB bf16 K^T [b][m][d]
constexpr size_t PM_B   = KT_B + 2097152;         // partial max (exp2 domain)
constexpr size_t PS_B   = PM_B + 32768;           // partial sum2
constexpr size_t C_B    = PS_B + 32768;           // 8 f32: C' = M' + log2(Z')
constexpr size_t WB_B   = C_B + 64;               // 320*256 bf16 packed weights
constexpr size_t BIAS_B = WB_B + 163840;          // 320 f32 biases

typedef __attribute__((ext_vector_type(8))) short short8;
typedef __attribute__((ext_vector_type(4))) float f32x4;

__device__ __forceinline__ unsigned bf16rne(float f) {
  unsigned u = __float_as_uint(f);
  return (u + 0x7fffu + ((u >> 16) & 1u)) >> 16;
}
__device__ __forceinline__ unsigned bfpack2(float lo, float hi) {
  union { __hip_bfloat162 h; unsigned u; } cv;
  cv.h.x = __float2bfloat16(lo);
  cv.h.y = __float2bfloat16(hi);
  return cv.u;
}

// ---------------------------------------------------------------------------
// Kernel 0: pack W1|W2*log2e|W3 -> bf16 Wb[320][256], biases -> f32[320]
// ---------------------------------------------------------------------------
__global__ __launch_bounds__(256) void prep_kernel(
    const float* __restrict__ W1, const float* __restrict__ b1,
    const float* __restrict__ W2, const float* __restrict__ b2,
    const float* __restrict__ W3, const float* __restrict__ b3,
    char* __restrict__ wsb)
{
  ushort* Wb = (ushort*)(wsb + WB_B);
  float* bias = (float*)(wsb + BIAS_B);
  const float LOG2E = 1.4426950408889634f;
  int idx = blockIdx.x * 256 + threadIdx.x;
  int r = idx >> 6, c4 = (idx & 63) * 4;
  float4 v; float sc = 1.0f;
  if (r < 256)      { v = *(const float4*)(W1 + (size_t)r * 256 + c4); }
  else if (r < 288) { v = *(const float4*)(W2 + (size_t)(r - 256) * 256 + c4); sc = LOG2E; }
  else              { v = *(const float4*)(W3 + (size_t)(r - 288) * 256 + c4); }
  ushort4 o;
  o.x = (ushort)bfpack2(v.x * sc, 0.f); o.y = (ushort)bfpack2(v.y * sc, 0.f);
  o.z = (ushort)bfpack2(v.z * sc, 0.f); o.w = (ushort)bfpack2(v.w * sc, 0.f);
  *(ushort4*)(Wb + (size_t)r * 256 + c4) = o;
  if (blockIdx.x == 0 && threadIdx.x < 320) {
    int q = threadIdx.x;
    bias[q] = q < 256 ? b1[q] : (q < 288 ? b2[q - 256] * LOG2E : b3[q - 288]);
  }
}

// ---------------------------------------------------------------------------
// Kernel 1: MFMA projections (unchanged)
// ---------------------------------------------------------------------------
__global__ __launch_bounds__(512) void proj_kernel(
    const float* __restrict__ x, char* __restrict__ wsb)
{
  __shared__ alignas(16) char xT[65536];    // [128 n][256 c] bf16, swz ((n&7)<<4)
  __shared__ alignas(16) char Wsh[40960];   // [320 o][64 c] bf16 chunk, swz ((o&7)<<4)
  const int bid = blockIdx.x;
  const int b = bid & 7, nt = bid >> 3;
  const int n0 = nt * 128;
  const int t = threadIdx.x, w = t >> 6, lane = t & 63;
  const int l4 = lane >> 4, l16 = lane & 15;
  const float* xb = x + (size_t)b * NC * SN;
  const ushort* Wb = (const ushort*)(wsb + WB_B);
  const float* bias = (const float*)(wsb + BIAS_B);
  ushort* vbuf  = (ushort*)(wsb + VB_B);
  ushort* qtbuf = (ushort*)(wsb + QT_B);
  ushort* ktbuf = (ushort*)(wsb + KT_B);

  {
    int cp = w * 16 + l16;
    int c  = cp * 2;
    int nb0 = l4 * 4;
#pragma unroll
    for (int ni = 0; ni < 8; ++ni) {
      int nB = ni * 16 + nb0;
      float4 a0 = *(const float4*)(xb + (size_t)c * SN + n0 + nB);
      float4 a1 = *(const float4*)(xb + (size_t)(c + 1) * SN + n0 + nB);
      const float* p0 = (const float*)&a0;
      const float* p1 = (const float*)&a1;
#pragma unroll
      for (int j = 0; j < 4; ++j) {
        int n = nB + j;
        *(uint*)(xT + n * 512 + ((cp * 4) ^ ((n & 7) << 4))) = bfpack2(p0[j], p1[j]);
      }
    }
  }
#pragma unroll
  for (int ii = 0; ii < 5; ++ii) {
    int slot = t + ii * 512;
    int r = slot >> 3, cc = slot & 7;
    *(uint4*)(Wsh + r * 128 + ((cc * 16) ^ ((r & 7) << 4))) =
        *(const uint4*)(Wb + (size_t)r * 256 + cc * 8);
  }
  __syncthreads();

  const int of_g = w >> 1;
  const int nf_g = w & 1;
  f32x4 acc[5][4] = {};

  for (int c4 = 0; c4 < 4; ++c4) {
#pragma unroll
    for (int kk = 0; kk < 2; ++kk) {
      short8 a[4];
#pragma unroll
      for (int nf = 0; nf < 4; ++nf) {
        int n = nf_g * 64 + nf * 16 + l16;
        a[nf] = *(const short8*)(xT + n * 512 +
                 ((c4 * 128 + kk * 64 + l4 * 16) ^ ((n & 7) << 4)));
      }
#pragma unroll
      for (int of = 0; of < 5; ++of) {
        int o = (of_g * 5 + of) * 16 + l16;
        short8 bf = *(const short8*)(Wsh + o * 128 +
                    ((kk * 64 + l4 * 16) ^ ((o & 7) << 4)));
#pragma unroll
        for (int nf = 0; nf < 4; ++nf)
          acc[of][nf] = __builtin_amdgcn_mfma_f32_16x16x32_bf16(a[nf], bf, acc[of][nf], 0, 0, 0);
      }
    }
    if (c4 < 3) {
      __syncthreads();
#pragma unroll
      for (int ii = 0; ii < 5; ++ii) {
        int slot = t + ii * 512;
        int r = slot >> 3, cc = slot & 7;
        *(uint4*)(Wsh + r * 128 + ((cc * 16) ^ ((r & 7) << 4))) =
            *(const uint4*)(Wb + (size_t)r * 256 + (c4 + 1) * 64 + cc * 8);
      }
      __syncthreads();
    }
  }

#pragma unroll
  for (int of = 0; of < 5; ++of) {
    int o = (of_g * 5 + of) * 16 + l16;
    float bv = bias[o];
#pragma unroll
    for (int nf = 0; nf < 4; ++nf) {
      int nb = nf_g * 64 + nf * 16 + l4 * 4;
      float v0 = acc[of][nf][0] + bv, v1 = acc[of][nf][1] + bv;
      float v2 = acc[of][nf][2] + bv, v3 = acc[of][nf][3] + bv;
      if (o < 256) {
        uint2 pk; pk.x = bfpack2(v0, v1); pk.y = bfpack2(v2, v3);
        *(uint2*)(vbuf + ((size_t)b * NC + o) * SN + n0 + nb) = pk;
      } else if (o < 288) {
        int d = o - 256;
        qtbuf[((size_t)b * SN + n0 + nb + 0) * ND + d] = (ushort)bf16rne(v0);
        qtbuf[((size_t)b * SN + n0 + nb + 1) * ND + d] = (ushort)bf16rne(v1);
        qtbuf[((size_t)b * SN + n0 + nb + 2) * ND + d] = (ushort)bf16rne(v2);
        qtbuf[((size_t)b * SN + n0 + nb + 3) * ND + d] = (ushort)bf16rne(v3);
      } else {
        int d = o - 288;
        ktbuf[((size_t)b * SN + n0 + nb + 0) * ND + d] = (ushort)bf16rne(v0);
        ktbuf[((size_t)b * SN + n0 + nb + 1) * ND + d] = (ushort)bf16rne(v1);
        ktbuf[((size_t)b * SN + n0 + nb + 2) * ND + d] = (ushort)bf16rne(v2);
        ktbuf[((size_t)b * SN + n0 + nb + 3) * ND + d] = (ushort)bf16rne(v3);
      }
    }
  }
}

// ---------------------------------------------------------------------------
// Kernel 2: QK^T tile stats in exp2 domain (unchanged)
// ---------------------------------------------------------------------------
__global__ __launch_bounds__(256) void qk_stats(
    const char* __restrict__ wsb, float* __restrict__ pm, float* __restrict__ ps)
{
  __shared__ alignas(16) char qt_s[128 * 64];
  __shared__ alignas(16) char kt_s[128 * 64];
  __shared__ float wm[4], wz[4];
  const int bid = blockIdx.x;
  const int b = bid & 7, ny = (bid >> 3) & 31, mx = bid >> 8;
  const int n0 = ny * 128, m0 = mx * 128;
  const int t = threadIdx.x, w = t >> 6, lane = t & 63;
  const int l4 = lane >> 4, l16 = lane & 15;
  const ushort* qtb = (const ushort*)(wsb + QT_B) + (size_t)b * SN * ND;
  const ushort* ktb = (const ushort*)(wsb + KT_B) + (size_t)b * SN * ND;
  {
    int row = t >> 1, db = (t & 1) * 32;
#pragma unroll
    for (int i = 0; i < 2; ++i) {
      int b16 = db + i * 16;
      int dst = row * 64 + (b16 ^ ((row & 3) << 4));
      *(uint4*)(qt_s + dst) = *(const uint4*)(qtb + (size_t)(n0 + row) * ND + b16 / 2);
      *(uint4*)(kt_s + dst) = *(const uint4*)(ktb + (size_t)(m0 + row) * ND + b16 / 2);
    }
  }
  __syncthreads();
  const f32x4 zf = {0.f, 0.f, 0.f, 0.f};
  short8 bfr[2];
#pragma unroll
  for (int j = 0; j < 2; ++j) {
    int mm = (w * 2 + j) * 16 + l16;
    bfr[j] = *(const short8*)(kt_s + mm * 64 + ((l4 * 16) ^ ((mm & 3) << 4)));
  }
  f32x4 sfr[8][2];
#pragma unroll
  for (int i = 0; i < 8; ++i) {
    int nn = i * 16 + l16;
    short8 af = *(const short8*)(qt_s + nn * 64 + ((l4 * 16) ^ ((nn & 3) << 4)));
#pragma unroll
    for (int j = 0; j < 2; ++j)
      sfr[i][j] = __builtin_amdgcn_mfma_f32_16x16x32_bf16(af, bfr[j], zf, 0, 0, 0);
  }
  float mt = -1e30f;
#pragma unroll
  for (int i = 0; i < 8; ++i)
#pragma unroll
    for (int j = 0; j < 2; ++j)
#pragma unroll
      for (int r = 0; r < 4; ++r) mt = fmaxf(mt, sfr[i][j][r]);
  float zt = 0.f;
#pragma unroll
  for (int i = 0; i < 8; ++i)
#pragma unroll
    for (int j = 0; j < 2; ++j)
#pragma unroll
      for (int r = 0; r < 4; ++r) zt += exp2f(sfr[i][j][r] - mt);

#pragma unroll
  for (int off = 1; off < 64; off <<= 1) {
    float m2 = __shfl_xor(mt, off);
    float z2 = __shfl_xor(zt, off);
    float M = fmaxf(mt, m2);
    zt = zt * exp2f(mt - M) + z2 * exp2f(m2 - M);
    mt = M;
  }
  if (lane == 0) { wm[w] = mt; wz[w] = zt; }
  __syncthreads();
  if (t == 0) {
    float m = wm[0], z = wz[0];
#pragma unroll
    for (int i = 1; i < 4; ++i) {
      float M = fmaxf(m, wm[i]);
      z = z * exp2f(m - M) + wz[i] * exp2f(wm[i] - M);
      m = M;
    }
    int idx = (b * 32 + ny) * 32 + mx;
    pm[idx] = m; ps[idx] = z;
  }
}

// ---------------------------------------------------------------------------
// Kernel 3: combine partials -> C'_b = M' + log2(Z')
// ---------------------------------------------------------------------------
__global__ __launch_bounds__(256) void reduce_kernel(char* __restrict__ wsb)
{
  const int b = blockIdx.x;
  const float* pm = (const float*)(wsb + PM_B) + (size_t)b * 1024;
  const float* ps = (const float*)(wsb + PS_B) + (size_t)b * 1024;
  const int t = threadIdx.x;
  float m = -1e30f, z = 0.f;
  for (int i = t; i < 1024; i += 256) {
    float m2 = pm[i], z2 = ps[i];
    float M = fmaxf(m, m2);
    z = z * exp2f(m - M) + z2 * exp2f(m2 - M);
    m = M;
  }
#pragma unroll
  for (int off = 1; off < 64; off <<= 1) {
    float m2 = __shfl_xor(m, off);
    float z2 = __shfl_xor(z, off);
    float M = fmaxf(m, m2);
    z = z * exp2f(m - M) + z2 * exp2f(m2 - M);
    m = M;
  }
  __shared__ float wm[4], wz[4];
  int w = t >> 6;
  if ((t & 63) == 0) { wm[w] = m; wz[w] = z; }
  __syncthreads();
  if (t == 0) {
    float M = wm[0], Z = wz[0];
#pragma unroll
    for (int i = 1; i < 4; ++i) {
      float Mn = fmaxf(M, wm[i]);
      Z = Z * exp2f(M - Mn) + wz[i] * exp2f(wm[i] - Mn);
      M = Mn;
    }
    ((float*)(wsb + C_B))[b] = M + log2f(Z);
  }
}

// ---------------------------------------------------------------------------
// Kernel 4: attention output. Block = 256 o x 64 m, 8 waves, chunk n=128.
// Round-4 schedule + fragment-major qt_s/as_s (conflict-free) + 3 blocks/CU
// (48 KB LDS, launch_bounds(512,6)). No register dbuf (round-6 spill lesson).
// ---------------------------------------------------------------------------
__global__ __launch_bounds__(512, 6) void attn_out(
    const char* __restrict__ wsb, const float* __restrict__ x, float* __restrict__ out)
{
  __shared__ alignas(16) char qt_s[2][8192];    // frag-major Q chunk [8 frags x 1KB], dbuf
  __shared__ alignas(16) char as_s[2][16384];   // frag-major P, dbuf
  const int bid = blockIdx.x;
  const int b = bid & 7, mt = bid >> 3;         // 8 batches x 64 m-tiles
  const int m0 = mt * 64;
  const int t = threadIdx.x, w = t >> 6, lane = t & 63;
  const int l4 = lane >> 4, l16 = lane & 15;
  const ushort* vb  = (const ushort*)(wsb + VB_B) + (size_t)b * NC * SN;
  const ushort* qtb = (const ushort*)(wsb + QT_B) + (size_t)b * SN * ND;
  const ushort* ktb = (const ushort*)(wsb + KT_B) + (size_t)b * SN * ND;
  const float Cb = ((const float*)(wsb + C_B))[b];

  const int mS_l = (w & 3) * 16 + l16;   // S-phase column (within 64-m tile)
  const int nh   = w >> 2;               // S-phase n-half (0/1)
  // K fragment for this wave's columns (resident, from global; read once)
  short8 bfr = *(const short8*)(ktb + (size_t)(m0 + mS_l) * ND + l4 * 8);

  // as_s frag-major write base (verified mapping, round 5)
  const int wr_base = mS_l * 16 + (l4 & 1) * 8;
  const int l4h = l4 >> 1;

  // qt_s frag-major staging: thread (qrow, qsl) -> frag qrow>>4, lane (qsl<<4)|(qrow&15)
  const int qrow = t >> 2, qsl = t & 3;
  const int qt_addr = (qrow >> 4) * 1024 + (((qsl << 4) | (qrow & 15)) << 4);

  // V row pointers (wave owns o-slice [w*32, w*32+32))
  const ushort* vrow0 = vb + (size_t)(w * 32 + l16) * SN + l4 * 8;
  const ushort* vrow1 = vrow0 + (size_t)16 * SN;

  const f32x4 zf = {0.f, 0.f, 0.f, 0.f};
  f32x4 acc[2][4] = {};

  // prologue: stage qt chunk 0
  *(uint4*)(qt_s[0] + qt_addr) = *(const uint4*)(qtb + (size_t)qrow * ND + qsl * 8);
  __syncthreads();

  for (int i = 0; i < 32; ++i) {
    const int cur = i & 1;
    // V loads for this chunk (consumed after the barrier; TLP covers latency)
    short8 vf[2][4];
#pragma unroll
    for (int kk = 0; kk < 4; ++kk) {
      vf[0][kk] = *(const short8*)(vrow0 + i * 128 + kk * 32);
      vf[1][kk] = *(const short8*)(vrow1 + i * 128 + kk * 32);
    }
    // q^T prefetch for next chunk
    uint4 qnext;
    const bool pf = (i < 31);
    if (pf) qnext = *(const uint4*)(qtb + (size_t)((i + 1) * 128 + qrow) * ND + qsl * 8);

    // S phase: 4 A-frags from frag-major LDS (conflict-free), MFMA, exp2, pack
#pragma unroll
    for (int ii = 0; ii < 4; ++ii) {
      int nf = nh * 4 + ii;
      short8 af = *(const short8*)(qt_s[cur] + nf * 1024 + lane * 16);
      f32x4 sv = __builtin_amdgcn_mfma_f32_16x16x32_bf16(af, bfr, zf, 0, 0, 0);
      uint2 pk;
      pk.x = bfpack2(exp2f(sv[0] - Cb), exp2f(sv[1] - Cb));
      pk.y = bfpack2(exp2f(sv[2] - Cb), exp2f(sv[3] - Cb));
      int addr = (nf >> 1) * 4096 + (((nf << 1) + l4h) & 3) * 1024 + wr_base;
      *(uint2*)(as_s[cur] + addr) = pk;
    }
    if (pf)
      *(uint4*)(qt_s[cur ^ 1] + qt_addr) = qnext;
    __syncthreads();

    // PV phase: frag-major reads (conflict-free) + MFMA cluster
    __builtin_amdgcn_s_setprio(1);
#pragma unroll
    for (int kk = 0; kk < 4; ++kk) {
      const char* base = as_s[cur] + kk * 4096 + l4 * 1024;
#pragma unroll
      for (int mf = 0; mf < 4; ++mf) {
        short8 paf = *(const short8*)(base + mf * 256 + l16 * 16);
        acc[0][mf] = __builtin_amdgcn_mfma_f32_16x16x32_bf16(vf[0][kk], paf, acc[0][mf], 0, 0, 0);
        acc[1][mf] = __builtin_amdgcn_mfma_f32_16x16x32_bf16(vf[1][kk], paf, acc[1][mf], 0, 0, 0);
      }
    }
    __builtin_amdgcn_s_setprio(0);
  }

  // epilogue: out = acc + x
#pragma unroll
  for (int of = 0; of < 2; ++of)
#pragma unroll
    for (int mf = 0; mf < 4; ++mf) {
      int m = m0 + mf * 16 + l16;
#pragma unroll
      for (int j = 0; j < 4; ++j) {
        int o = w * 32 + of * 16 + l4 * 4 + j;
        size_t idx = ((size_t)b * NC + o) * SN + m;
        out[idx] = acc[of][mf][j] + x[idx];
      }
    }
}

extern "C" void kernel_launch(void* const* d_in, const int* in_sizes, int n_in,
                              void* d_out, int out_size, void* d_ws, size_t ws_size,
                              hipStream_t stream)
{
  const float* x  = (const float*)d_in[0];
  const float* W1 = (const float*)d_in[1];
  const float* b1 = (const float*)d_in[2];
  const float* W2 = (const float*)d_in[3];
  const float* b2 = (const float*)d_in[4];
  const float* W3 = (const float*)d_in[5];
  const float* b3 = (const float*)d_in[6];
  char* wsb  = (char*)d_ws;
  float* out = (float*)d_out;

  prep_kernel<<<80, 256, 0, stream>>>(W1, b1, W2, b2, W3, b3, wsb);
  proj_kernel<<<256, 512, 0, stream>>>(x, wsb);
  qk_stats<<<8192, 256, 0, stream>>>(wsb, (float*)(wsb + PM_B), (float*)(wsb + PS_B));
  reduce_kernel<<<NBATCH, 256, 0, stream>>>(wsb);
  attn_out<<<512, 512, 0, stream>>>(wsb, x, out);
}

// Round 8
// 324.165 us; speedup vs baseline: 1.1337x; 1.1337x over previous
//
#include <hip/hip_runtime.h>
#include <hip/hip_bf16.h>
#include <math.h>

#define NBATCH 8
#define NC 256
#define ND 32
#define SN 4096

// Workspace byte offsets
constexpr size_t VB_B   = 0;                      // 16 MB bf16 V [b][o][n]
constexpr size_t QT_B   = 16777216;               // 2 MB bf16 Q^T [b][n][d] (pre-scaled by log2e)
constexpr size_t KT_B   = QT_B + 2097152;         // 2 MB bf16 K^T [b][m][d]
constexpr size_t PM_B   = KT_B + 2097152;         // partial max (exp2 domain)
constexpr size_t PS_B   = PM_B + 32768;           // partial sum2
constexpr size_t C_B    = PS_B + 32768;           // 8 f32: C' = M' + log2(Z')
constexpr size_t WB_B   = C_B + 64;               // 320*256 bf16 packed weights
constexpr size_t BIAS_B = WB_B + 163840;          // 320 f32 biases

typedef __attribute__((ext_vector_type(8))) short short8;
typedef __attribute__((ext_vector_type(4))) float f32x4;

__device__ __forceinline__ unsigned bf16rne(float f) {
  unsigned u = __float_as_uint(f);
  return (u + 0x7fffu + ((u >> 16) & 1u)) >> 16;
}
__device__ __forceinline__ unsigned bfpack2(float lo, float hi) {
  union { __hip_bfloat162 h; unsigned u; } cv;
  cv.h.x = __float2bfloat16(lo);
  cv.h.y = __float2bfloat16(hi);
  return cv.u;
}

// ---------------------------------------------------------------------------
// Kernel 0: pack W1|W2*log2e|W3 -> bf16 Wb[320][256], biases -> f32[320]
// ---------------------------------------------------------------------------
__global__ __launch_bounds__(256) void prep_kernel(
    const float* __restrict__ W1, const float* __restrict__ b1,
    const float* __restrict__ W2, const float* __restrict__ b2,
    const float* __restrict__ W3, const float* __restrict__ b3,
    char* __restrict__ wsb)
{
  ushort* Wb = (ushort*)(wsb + WB_B);
  float* bias = (float*)(wsb + BIAS_B);
  const float LOG2E = 1.4426950408889634f;
  int idx = blockIdx.x * 256 + threadIdx.x;
  int r = idx >> 6, c4 = (idx & 63) * 4;
  float4 v; float sc = 1.0f;
  if (r < 256)      { v = *(const float4*)(W1 + (size_t)r * 256 + c4); }
  else if (r < 288) { v = *(const float4*)(W2 + (size_t)(r - 256) * 256 + c4); sc = LOG2E; }
  else              { v = *(const float4*)(W3 + (size_t)(r - 288) * 256 + c4); }
  ushort4 o;
  o.x = (ushort)bfpack2(v.x * sc, 0.f); o.y = (ushort)bfpack2(v.y * sc, 0.f);
  o.z = (ushort)bfpack2(v.z * sc, 0.f); o.w = (ushort)bfpack2(v.w * sc, 0.f);
  *(ushort4*)(Wb + (size_t)r * 256 + c4) = o;
  if (blockIdx.x == 0 && threadIdx.x < 320) {
    int q = threadIdx.x;
    bias[q] = q < 256 ? b1[q] : (q < 288 ? b2[q - 256] * LOG2E : b3[q - 288]);
  }
}

// ---------------------------------------------------------------------------
// Kernel 1: MFMA projections (unchanged)
// ---------------------------------------------------------------------------
__global__ __launch_bounds__(512) void proj_kernel(
    const float* __restrict__ x, char* __restrict__ wsb)
{
  __shared__ alignas(16) char xT[65536];    // [128 n][256 c] bf16, swz ((n&7)<<4)
  __shared__ alignas(16) char Wsh[40960];   // [320 o][64 c] bf16 chunk, swz ((o&7)<<4)
  const int bid = blockIdx.x;
  const int b = bid & 7, nt = bid >> 3;
  const int n0 = nt * 128;
  const int t = threadIdx.x, w = t >> 6, lane = t & 63;
  const int l4 = lane >> 4, l16 = lane & 15;
  const float* xb = x + (size_t)b * NC * SN;
  const ushort* Wb = (const ushort*)(wsb + WB_B);
  const float* bias = (const float*)(wsb + BIAS_B);
  ushort* vbuf  = (ushort*)(wsb + VB_B);
  ushort* qtbuf = (ushort*)(wsb + QT_B);
  ushort* ktbuf = (ushort*)(wsb + KT_B);

  {
    int cp = w * 16 + l16;
    int c  = cp * 2;
    int nb0 = l4 * 4;
#pragma unroll
    for (int ni = 0; ni < 8; ++ni) {
      int nB = ni * 16 + nb0;
      float4 a0 = *(const float4*)(xb + (size_t)c * SN + n0 + nB);
      float4 a1 = *(const float4*)(xb + (size_t)(c + 1) * SN + n0 + nB);
      const float* p0 = (const float*)&a0;
      const float* p1 = (const float*)&a1;
#pragma unroll
      for (int j = 0; j < 4; ++j) {
        int n = nB + j;
        *(uint*)(xT + n * 512 + ((cp * 4) ^ ((n & 7) << 4))) = bfpack2(p0[j], p1[j]);
      }
    }
  }
#pragma unroll
  for (int ii = 0; ii < 5; ++ii) {
    int slot = t + ii * 512;
    int r = slot >> 3, cc = slot & 7;
    *(uint4*)(Wsh + r * 128 + ((cc * 16) ^ ((r & 7) << 4))) =
        *(const uint4*)(Wb + (size_t)r * 256 + cc * 8);
  }
  __syncthreads();

  const int of_g = w >> 1;
  const int nf_g = w & 1;
  f32x4 acc[5][4] = {};

  for (int c4 = 0; c4 < 4; ++c4) {
#pragma unroll
    for (int kk = 0; kk < 2; ++kk) {
      short8 a[4];
#pragma unroll
      for (int nf = 0; nf < 4; ++nf) {
        int n = nf_g * 64 + nf * 16 + l16;
        a[nf] = *(const short8*)(xT + n * 512 +
                 ((c4 * 128 + kk * 64 + l4 * 16) ^ ((n & 7) << 4)));
      }
#pragma unroll
      for (int of = 0; of < 5; ++of) {
        int o = (of_g * 5 + of) * 16 + l16;
        short8 bf = *(const short8*)(Wsh + o * 128 +
                    ((kk * 64 + l4 * 16) ^ ((o & 7) << 4)));
#pragma unroll
        for (int nf = 0; nf < 4; ++nf)
          acc[of][nf] = __builtin_amdgcn_mfma_f32_16x16x32_bf16(a[nf], bf, acc[of][nf], 0, 0, 0);
      }
    }
    if (c4 < 3) {
      __syncthreads();
#pragma unroll
      for (int ii = 0; ii < 5; ++ii) {
        int slot = t + ii * 512;
        int r = slot >> 3, cc = slot & 7;
        *(uint4*)(Wsh + r * 128 + ((cc * 16) ^ ((r & 7) << 4))) =
            *(const uint4*)(Wb + (size_t)r * 256 + (c4 + 1) * 64 + cc * 8);
      }
      __syncthreads();
    }
  }

#pragma unroll
  for (int of = 0; of < 5; ++of) {
    int o = (of_g * 5 + of) * 16 + l16;
    float bv = bias[o];
#pragma unroll
    for (int nf = 0; nf < 4; ++nf) {
      int nb = nf_g * 64 + nf * 16 + l4 * 4;
      float v0 = acc[of][nf][0] + bv, v1 = acc[of][nf][1] + bv;
      float v2 = acc[of][nf][2] + bv, v3 = acc[of][nf][3] + bv;
      if (o < 256) {
        uint2 pk; pk.x = bfpack2(v0, v1); pk.y = bfpack2(v2, v3);
        *(uint2*)(vbuf + ((size_t)b * NC + o) * SN + n0 + nb) = pk;
      } else if (o < 288) {
        int d = o - 256;
        qtbuf[((size_t)b * SN + n0 + nb + 0) * ND + d] = (ushort)bf16rne(v0);
        qtbuf[((size_t)b * SN + n0 + nb + 1) * ND + d] = (ushort)bf16rne(v1);
        qtbuf[((size_t)b * SN + n0 + nb + 2) * ND + d] = (ushort)bf16rne(v2);
        qtbuf[((size_t)b * SN + n0 + nb + 3) * ND + d] = (ushort)bf16rne(v3);
      } else {
        int d = o - 288;
        ktbuf[((size_t)b * SN + n0 + nb + 0) * ND + d] = (ushort)bf16rne(v0);
        ktbuf[((size_t)b * SN + n0 + nb + 1) * ND + d] = (ushort)bf16rne(v1);
        ktbuf[((size_t)b * SN + n0 + nb + 2) * ND + d] = (ushort)bf16rne(v2);
        ktbuf[((size_t)b * SN + n0 + nb + 3) * ND + d] = (ushort)bf16rne(v3);
      }
    }
  }
}

// ---------------------------------------------------------------------------
// Kernel 2: QK^T tile stats in exp2 domain (unchanged)
// ---------------------------------------------------------------------------
__global__ __launch_bounds__(256) void qk_stats(
    const char* __restrict__ wsb, float* __restrict__ pm, float* __restrict__ ps)
{
  __shared__ alignas(16) char qt_s[128 * 64];
  __shared__ alignas(16) char kt_s[128 * 64];
  __shared__ float wm[4], wz[4];
  const int bid = blockIdx.x;
  const int b = bid & 7, ny = (bid >> 3) & 31, mx = bid >> 8;
  const int n0 = ny * 128, m0 = mx * 128;
  const int t = threadIdx.x, w = t >> 6, lane = t & 63;
  const int l4 = lane >> 4, l16 = lane & 15;
  const ushort* qtb = (const ushort*)(wsb + QT_B) + (size_t)b * SN * ND;
  const ushort* ktb = (const ushort*)(wsb + KT_B) + (size_t)b * SN * ND;
  {
    int row = t >> 1, db = (t & 1) * 32;
#pragma unroll
    for (int i = 0; i < 2; ++i) {
      int b16 = db + i * 16;
      int dst = row * 64 + (b16 ^ ((row & 3) << 4));
      *(uint4*)(qt_s + dst) = *(const uint4*)(qtb + (size_t)(n0 + row) * ND + b16 / 2);
      *(uint4*)(kt_s + dst) = *(const uint4*)(ktb + (size_t)(m0 + row) * ND + b16 / 2);
    }
  }
  __syncthreads();
  const f32x4 zf = {0.f, 0.f, 0.f, 0.f};
  short8 bfr[2];
#pragma unroll
  for (int j = 0; j < 2; ++j) {
    int mm = (w * 2 + j) * 16 + l16;
    bfr[j] = *(const short8*)(kt_s + mm * 64 + ((l4 * 16) ^ ((mm & 3) << 4)));
  }
  f32x4 sfr[8][2];
#pragma unroll
  for (int i = 0; i < 8; ++i) {
    int nn = i * 16 + l16;
    short8 af = *(const short8*)(qt_s + nn * 64 + ((l4 * 16) ^ ((nn & 3) << 4)));
#pragma unroll
    for (int j = 0; j < 2; ++j)
      sfr[i][j] = __builtin_amdgcn_mfma_f32_16x16x32_bf16(af, bfr[j], zf, 0, 0, 0);
  }
  float mt = -1e30f;
#pragma unroll
  for (int i = 0; i < 8; ++i)
#pragma unroll
    for (int j = 0; j < 2; ++j)
#pragma unroll
      for (int r = 0; r < 4; ++r) mt = fmaxf(mt, sfr[i][j][r]);
  float zt = 0.f;
#pragma unroll
  for (int i = 0; i < 8; ++i)
#pragma unroll
    for (int j = 0; j < 2; ++j)
#pragma unroll
      for (int r = 0; r < 4; ++r) zt += exp2f(sfr[i][j][r] - mt);

#pragma unroll
  for (int off = 1; off < 64; off <<= 1) {
    float m2 = __shfl_xor(mt, off);
    float z2 = __shfl_xor(zt, off);
    float M = fmaxf(mt, m2);
    zt = zt * exp2f(mt - M) + z2 * exp2f(m2 - M);
    mt = M;
  }
  if (lane == 0) { wm[w] = mt; wz[w] = zt; }
  __syncthreads();
  if (t == 0) {
    float m = wm[0], z = wz[0];
#pragma unroll
    for (int i = 1; i < 4; ++i) {
      float M = fmaxf(m, wm[i]);
      z = z * exp2f(m - M) + wz[i] * exp2f(wm[i] - M);
      m = M;
    }
    int idx = (b * 32 + ny) * 32 + mx;
    pm[idx] = m; ps[idx] = z;
  }
}

// ---------------------------------------------------------------------------
// Kernel 3: combine partials -> C'_b = M' + log2(Z')
// ---------------------------------------------------------------------------
__global__ __launch_bounds__(256) void reduce_kernel(char* __restrict__ wsb)
{
  const int b = blockIdx.x;
  const float* pm = (const float*)(wsb + PM_B) + (size_t)b * 1024;
  const float* ps = (const float*)(wsb + PS_B) + (size_t)b * 1024;
  const int t = threadIdx.x;
  float m = -1e30f, z = 0.f;
  for (int i = t; i < 1024; i += 256) {
    float m2 = pm[i], z2 = ps[i];
    float M = fmaxf(m, m2);
    z = z * exp2f(m - M) + z2 * exp2f(m2 - M);
    m = M;
  }
#pragma unroll
  for (int off = 1; off < 64; off <<= 1) {
    float m2 = __shfl_xor(m, off);
    float z2 = __shfl_xor(z, off);
    float M = fmaxf(m, m2);
    z = z * exp2f(m - M) + z2 * exp2f(m2 - M);
    m = M;
  }
  __shared__ float wm[4], wz[4];
  int w = t >> 6;
  if ((t & 63) == 0) { wm[w] = m; wz[w] = z; }
  __syncthreads();
  if (t == 0) {
    float M = wm[0], Z = wz[0];
#pragma unroll
    for (int i = 1; i < 4; ++i) {
      float Mn = fmaxf(M, wm[i]);
      Z = Z * exp2f(M - Mn) + wz[i] * exp2f(wm[i] - Mn);
      M = Mn;
    }
    ((float*)(wsb + C_B))[b] = M + log2f(Z);
  }
}

// ---------------------------------------------------------------------------
// Kernel 4: attention output. Block = 256 o x 32 m, 4 waves (256 thr),
// chunk n=128, grid 1024 (8 b x 128 mt) -> 4 blocks/CU. Round-4 schedule.
// Fragment-major qt_s/as_s: all MFMA-frag LDS reads are lane*16B (no conflict).
//   qt_s frag u (0..7): lane l holds Q[n=u*16+l16][d=l4*8..+7]
//   as_s frag f=kk*2+mf: lane l holds P^T[m=mf*16+l16][n=kk*32+l4*8..+7] bf16
// ---------------------------------------------------------------------------
__global__ __launch_bounds__(256, 4) void attn_out(
    const char* __restrict__ wsb, const float* __restrict__ x, float* __restrict__ out)
{
  __shared__ alignas(16) char qt_s[2][8192];   // 8 frags x 1KB, dbuf
  __shared__ alignas(16) char as_s[2][8192];   // 8 frags x 1KB, dbuf
  const int bid = blockIdx.x;
  const int b = bid & 7, mt = bid >> 3;        // 8 batches x 128 m-tiles
  const int m0 = mt * 32;
  const int t = threadIdx.x, w = t >> 6, lane = t & 63;
  const int l4 = lane >> 4, l16 = lane & 15;
  const ushort* vb  = (const ushort*)(wsb + VB_B) + (size_t)b * NC * SN;
  const ushort* qtb = (const ushort*)(wsb + QT_B) + (size_t)b * SN * ND;
  const ushort* ktb = (const ushort*)(wsb + KT_B) + (size_t)b * SN * ND;
  const float Cb = ((const float*)(wsb + C_B))[b];

  // S-phase role: wave -> (m-frag, n-half)
  const int mfS = w & 1;
  const int nh  = w >> 1;
  const int mS_l = mfS * 16 + l16;
  short8 bfr = *(const short8*)(ktb + (size_t)(m0 + mS_l) * ND + l4 * 8);

  // as_s write addr(u) = (u>>1)*2048 + (u&1)*512 + (l4>>1)*256 + mfS*1024
  //                      + l16*16 + (l4&1)*8   [derived & element-checked]
  const int as_wbase = mfS * 1024 + (l4 >> 1) * 256 + l16 * 16 + (l4 & 1) * 8;

  // qt staging: thread covers row qrow = t>>1, d-halves qsl = ii*2 + (t&1)
  const int qrow = t >> 1, qpar = t & 1;

  // PV: wave owns o-slice [w*64, w*64+64)
  const ushort* vrow = vb + (size_t)(w * 64 + l16) * SN + l4 * 8;

  const f32x4 zf = {0.f, 0.f, 0.f, 0.f};
  f32x4 acc[4][2] = {};

  // prologue: stage qt chunk 0
#pragma unroll
  for (int ii = 0; ii < 2; ++ii) {
    int qsl = ii * 2 + qpar;
    *(uint4*)(qt_s[0] + (qrow >> 4) * 1024 + ((qsl * 16 + (qrow & 15)) << 4)) =
        *(const uint4*)(qtb + (size_t)qrow * ND + qsl * 8);
  }
  __syncthreads();

  for (int i = 0; i < 32; ++i) {
    const int cur = i & 1;
    // V loads for this chunk (drained by the barrier; consumed in PV)
    short8 vf[4][4];
#pragma unroll
    for (int kk = 0; kk < 4; ++kk)
#pragma unroll
      for (int of = 0; of < 4; ++of)
        vf[kk][of] = *(const short8*)(vrow + (size_t)(of * 16) * SN + i * 128 + kk * 32);
    // q^T prefetch for next chunk
    uint4 qnext[2];
    const bool pf = (i < 31);
    if (pf) {
#pragma unroll
      for (int ii = 0; ii < 2; ++ii) {
        int qsl = ii * 2 + qpar;
        qnext[ii] = *(const uint4*)(qtb + (size_t)((i + 1) * 128 + qrow) * ND + qsl * 8);
      }
    }

    // S phase: 4 frag-major reads, MFMA, exp2, pack, frag-major write
#pragma unroll
    for (int ii = 0; ii < 4; ++ii) {
      int u = nh * 4 + ii;
      short8 af = *(const short8*)(qt_s[cur] + u * 1024 + lane * 16);
      f32x4 sv = __builtin_amdgcn_mfma_f32_16x16x32_bf16(af, bfr, zf, 0, 0, 0);
      uint2 pk;
      pk.x = bfpack2(exp2f(sv[0] - Cb), exp2f(sv[1] - Cb));
      pk.y = bfpack2(exp2f(sv[2] - Cb), exp2f(sv[3] - Cb));
      *(uint2*)(as_s[cur] + (u >> 1) * 2048 + (u & 1) * 512 + as_wbase) = pk;
    }
    if (pf) {
#pragma unroll
      for (int ii = 0; ii < 2; ++ii) {
        int qsl = ii * 2 + qpar;
        *(uint4*)(qt_s[cur ^ 1] + (qrow >> 4) * 1024 + ((qsl * 16 + (qrow & 15)) << 4)) =
            qnext[ii];
      }
    }
    __syncthreads();

    // PV phase: frag-major reads (lane*16B, conflict-free) + MFMA cluster
    __builtin_amdgcn_s_setprio(1);
#pragma unroll
    for (int kk = 0; kk < 4; ++kk) {
#pragma unroll
      for (int mf = 0; mf < 2; ++mf) {
        short8 paf = *(const short8*)(as_s[cur] + (kk * 2 + mf) * 1024 + lane * 16);
#pragma unroll
        for (int of = 0; of < 4; ++of)
          acc[of][mf] = __builtin_amdgcn_mfma_f32_16x16x32_bf16(vf[kk][of], paf, acc[of][mf], 0, 0, 0);
      }
    }
    __builtin_amdgcn_s_setprio(0);
  }

  // epilogue: out = acc + x
#pragma unroll
  for (int of = 0; of < 4; ++of)
#pragma unroll
    for (int mf = 0; mf < 2; ++mf) {
      int m = m0 + mf * 16 + l16;
#pragma unroll
      for (int j = 0; j < 4; ++j) {
        int o = w * 64 + of * 16 + l4 * 4 + j;
        size_t idx = ((size_t)b * NC + o) * SN + m;
        out[idx] = acc[of][mf][j] + x[idx];
      }
    }
}

extern "C" void kernel_launch(void* const* d_in, const int* in_sizes, int n_in,
                              void* d_out, int out_size, void* d_ws, size_t ws_size,
                              hipStream_t stream)
{
  const float* x  = (const float*)d_in[0];
  const float* W1 = (const float*)d_in[1];
  const float* b1 = (const float*)d_in[2];
  const float* W2 = (const float*)d_in[3];
  const float* b2 = (const float*)d_in[4];
  const float* W3 = (const float*)d_in[5];
  const float* b3 = (const float*)d_in[6];
  char* wsb  = (char*)d_ws;
  float* out = (float*)d_out;

  prep_kernel<<<80, 256, 0, stream>>>(W1, b1, W2, b2, W3, b3, wsb);
  proj_kernel<<<256, 512, 0, stream>>>(x, wsb);
  qk_stats<<<8192, 256, 0, stream>>>(wsb, (float*)(wsb + PM_B), (float*)(wsb + PS_B));
  reduce_kernel<<<NBATCH, 256, 0, stream>>>(wsb);
  attn_out<<<1024, 256, 0, stream>>>(wsb, x, out);
}

// Round 9
// 224.531 us; speedup vs baseline: 1.6368x; 1.4437x over previous
//
#include <hip/hip_runtime.h>
#include <hip/hip_bf16.h>
#include <math.h>

#define NBATCH 8
#define NC 256
#define ND 32
#define SN 4096

// Workspace byte offsets
constexpr size_t VB_B   = 0;                      // 16 MB bf16 V [b][o][n]
constexpr size_t QT_B   = 16777216;               // 2 MB bf16 Q^T [b][n][d] (pre-scaled by log2e)
constexpr size_t KT_B   = QT_B + 2097152;         // 2 MB bf16 K^T [b][m][d]
constexpr size_t PM_B   = KT_B + 2097152;         // partial max (exp2 domain)
constexpr size_t PS_B   = PM_B + 32768;           // partial sum2
constexpr size_t C_B    = PS_B + 32768;           // 8 f32: C' = M' + log2(Z')
constexpr size_t WB_B   = C_B + 64;               // 320*256 bf16 packed weights
constexpr size_t BIAS_B = WB_B + 163840;          // 320 f32 biases
constexpr size_t PB_B   = BIAS_B + 1280;          // 16.7 MB bf16 partial O [b][o][m] (half 0)
// total ws use ~38 MB (<= 42 MB proven in round 1)

typedef __attribute__((ext_vector_type(8))) short short8;
typedef __attribute__((ext_vector_type(4))) float f32x4;

__device__ __forceinline__ unsigned bf16rne(float f) {
  unsigned u = __float_as_uint(f);
  return (u + 0x7fffu + ((u >> 16) & 1u)) >> 16;
}
__device__ __forceinline__ unsigned bfpack2(float lo, float hi) {
  union { __hip_bfloat162 h; unsigned u; } cv;
  cv.h.x = __float2bfloat16(lo);
  cv.h.y = __float2bfloat16(hi);
  return cv.u;
}

// ---------------------------------------------------------------------------
// Kernel 0: pack W1|W2*log2e|W3 -> bf16 Wb[320][256], biases -> f32[320]
// ---------------------------------------------------------------------------
__global__ __launch_bounds__(256) void prep_kernel(
    const float* __restrict__ W1, const float* __restrict__ b1,
    const float* __restrict__ W2, const float* __restrict__ b2,
    const float* __restrict__ W3, const float* __restrict__ b3,
    char* __restrict__ wsb)
{
  ushort* Wb = (ushort*)(wsb + WB_B);
  float* bias = (float*)(wsb + BIAS_B);
  const float LOG2E = 1.4426950408889634f;
  int idx = blockIdx.x * 256 + threadIdx.x;
  int r = idx >> 6, c4 = (idx & 63) * 4;
  float4 v; float sc = 1.0f;
  if (r < 256)      { v = *(const float4*)(W1 + (size_t)r * 256 + c4); }
  else if (r < 288) { v = *(const float4*)(W2 + (size_t)(r - 256) * 256 + c4); sc = LOG2E; }
  else              { v = *(const float4*)(W3 + (size_t)(r - 288) * 256 + c4); }
  ushort4 o;
  o.x = (ushort)bf16rne(v.x * sc); o.y = (ushort)bf16rne(v.y * sc);
  o.z = (ushort)bf16rne(v.z * sc); o.w = (ushort)bf16rne(v.w * sc);
  *(ushort4*)(Wb + (size_t)r * 256 + c4) = o;
  if (blockIdx.x == 0 && threadIdx.x < 320) {
    int q = threadIdx.x;
    bias[q] = q < 256 ? b1[q] : (q < 288 ? b2[q - 256] * LOG2E : b3[q - 288]);
  }
}

// ---------------------------------------------------------------------------
// Kernel 1: MFMA projections (unchanged)
// ---------------------------------------------------------------------------
__global__ __launch_bounds__(512) void proj_kernel(
    const float* __restrict__ x, char* __restrict__ wsb)
{
  __shared__ alignas(16) char xT[65536];    // [128 n][256 c] bf16, swz ((n&7)<<4)
  __shared__ alignas(16) char Wsh[40960];   // [320 o][64 c] bf16 chunk, swz ((o&7)<<4)
  const int bid = blockIdx.x;
  const int b = bid & 7, nt = bid >> 3;
  const int n0 = nt * 128;
  const int t = threadIdx.x, w = t >> 6, lane = t & 63;
  const int l4 = lane >> 4, l16 = lane & 15;
  const float* xb = x + (size_t)b * NC * SN;
  const ushort* Wb = (const ushort*)(wsb + WB_B);
  const float* bias = (const float*)(wsb + BIAS_B);
  ushort* vbuf  = (ushort*)(wsb + VB_B);
  ushort* qtbuf = (ushort*)(wsb + QT_B);
  ushort* ktbuf = (ushort*)(wsb + KT_B);

  {
    int cp = w * 16 + l16;
    int c  = cp * 2;
    int nb0 = l4 * 4;
#pragma unroll
    for (int ni = 0; ni < 8; ++ni) {
      int nB = ni * 16 + nb0;
      float4 a0 = *(const float4*)(xb + (size_t)c * SN + n0 + nB);
      float4 a1 = *(const float4*)(xb + (size_t)(c + 1) * SN + n0 + nB);
      const float* p0 = (const float*)&a0;
      const float* p1 = (const float*)&a1;
#pragma unroll
      for (int j = 0; j < 4; ++j) {
        int n = nB + j;
        *(uint*)(xT + n * 512 + ((cp * 4) ^ ((n & 7) << 4))) = bfpack2(p0[j], p1[j]);
      }
    }
  }
#pragma unroll
  for (int ii = 0; ii < 5; ++ii) {
    int slot = t + ii * 512;
    int r = slot >> 3, cc = slot & 7;
    *(uint4*)(Wsh + r * 128 + ((cc * 16) ^ ((r & 7) << 4))) =
        *(const uint4*)(Wb + (size_t)r * 256 + cc * 8);
  }
  __syncthreads();

  const int of_g = w >> 1;
  const int nf_g = w & 1;
  f32x4 acc[5][4] = {};

  for (int c4 = 0; c4 < 4; ++c4) {
#pragma unroll
    for (int kk = 0; kk < 2; ++kk) {
      short8 a[4];
#pragma unroll
      for (int nf = 0; nf < 4; ++nf) {
        int n = nf_g * 64 + nf * 16 + l16;
        a[nf] = *(const short8*)(xT + n * 512 +
                 ((c4 * 128 + kk * 64 + l4 * 16) ^ ((n & 7) << 4)));
      }
#pragma unroll
      for (int of = 0; of < 5; ++of) {
        int o = (of_g * 5 + of) * 16 + l16;
        short8 bf = *(const short8*)(Wsh + o * 128 +
                    ((kk * 64 + l4 * 16) ^ ((o & 7) << 4)));
#pragma unroll
        for (int nf = 0; nf < 4; ++nf)
          acc[of][nf] = __builtin_amdgcn_mfma_f32_16x16x32_bf16(a[nf], bf, acc[of][nf], 0, 0, 0);
      }
    }
    if (c4 < 3) {
      __syncthreads();
#pragma unroll
      for (int ii = 0; ii < 5; ++ii) {
        int slot = t + ii * 512;
        int r = slot >> 3, cc = slot & 7;
        *(uint4*)(Wsh + r * 128 + ((cc * 16) ^ ((r & 7) << 4))) =
            *(const uint4*)(Wb + (size_t)r * 256 + (c4 + 1) * 64 + cc * 8);
      }
      __syncthreads();
    }
  }

#pragma unroll
  for (int of = 0; of < 5; ++of) {
    int o = (of_g * 5 + of) * 16 + l16;
    float bv = bias[o];
#pragma unroll
    for (int nf = 0; nf < 4; ++nf) {
      int nb = nf_g * 64 + nf * 16 + l4 * 4;
      float v0 = acc[of][nf][0] + bv, v1 = acc[of][nf][1] + bv;
      float v2 = acc[of][nf][2] + bv, v3 = acc[of][nf][3] + bv;
      if (o < 256) {
        uint2 pk; pk.x = bfpack2(v0, v1); pk.y = bfpack2(v2, v3);
        *(uint2*)(vbuf + ((size_t)b * NC + o) * SN + n0 + nb) = pk;
      } else if (o < 288) {
        int d = o - 256;
        qtbuf[((size_t)b * SN + n0 + nb + 0) * ND + d] = (ushort)bf16rne(v0);
        qtbuf[((size_t)b * SN + n0 + nb + 1) * ND + d] = (ushort)bf16rne(v1);
        qtbuf[((size_t)b * SN + n0 + nb + 2) * ND + d] = (ushort)bf16rne(v2);
        qtbuf[((size_t)b * SN + n0 + nb + 3) * ND + d] = (ushort)bf16rne(v3);
      } else {
        int d = o - 288;
        ktbuf[((size_t)b * SN + n0 + nb + 0) * ND + d] = (ushort)bf16rne(v0);
        ktbuf[((size_t)b * SN + n0 + nb + 1) * ND + d] = (ushort)bf16rne(v1);
        ktbuf[((size_t)b * SN + n0 + nb + 2) * ND + d] = (ushort)bf16rne(v2);
        ktbuf[((size_t)b * SN + n0 + nb + 3) * ND + d] = (ushort)bf16rne(v3);
      }
    }
  }
}

// ---------------------------------------------------------------------------
// Kernel 2: QK^T tile stats in exp2 domain (unchanged)
// ---------------------------------------------------------------------------
__global__ __launch_bounds__(256) void qk_stats(
    const char* __restrict__ wsb, float* __restrict__ pm, float* __restrict__ ps)
{
  __shared__ alignas(16) char qt_s[128 * 64];
  __shared__ alignas(16) char kt_s[128 * 64];
  __shared__ float wm[4], wz[4];
  const int bid = blockIdx.x;
  const int b = bid & 7, ny = (bid >> 3) & 31, mx = bid >> 8;
  const int n0 = ny * 128, m0 = mx * 128;
  const int t = threadIdx.x, w = t >> 6, lane = t & 63;
  const int l4 = lane >> 4, l16 = lane & 15;
  const ushort* qtb = (const ushort*)(wsb + QT_B) + (size_t)b * SN * ND;
  const ushort* ktb = (const ushort*)(wsb + KT_B) + (size_t)b * SN * ND;
  {
    int row = t >> 1, db = (t & 1) * 32;
#pragma unroll
    for (int i = 0; i < 2; ++i) {
      int b16 = db + i * 16;
      int dst = row * 64 + (b16 ^ ((row & 3) << 4));
      *(uint4*)(qt_s + dst) = *(const uint4*)(qtb + (size_t)(n0 + row) * ND + b16 / 2);
      *(uint4*)(kt_s + dst) = *(const uint4*)(ktb + (size_t)(m0 + row) * ND + b16 / 2);
    }
  }
  __syncthreads();
  const f32x4 zf = {0.f, 0.f, 0.f, 0.f};
  short8 bfr[2];
#pragma unroll
  for (int j = 0; j < 2; ++j) {
    int mm = (w * 2 + j) * 16 + l16;
    bfr[j] = *(const short8*)(kt_s + mm * 64 + ((l4 * 16) ^ ((mm & 3) << 4)));
  }
  f32x4 sfr[8][2];
#pragma unroll
  for (int i = 0; i < 8; ++i) {
    int nn = i * 16 + l16;
    short8 af = *(const short8*)(qt_s + nn * 64 + ((l4 * 16) ^ ((nn & 3) << 4)));
#pragma unroll
    for (int j = 0; j < 2; ++j)
      sfr[i][j] = __builtin_amdgcn_mfma_f32_16x16x32_bf16(af, bfr[j], zf, 0, 0, 0);
  }
  float mt = -1e30f;
#pragma unroll
  for (int i = 0; i < 8; ++i)
#pragma unroll
    for (int j = 0; j < 2; ++j)
#pragma unroll
      for (int r = 0; r < 4; ++r) mt = fmaxf(mt, sfr[i][j][r]);
  float zt = 0.f;
#pragma unroll
  for (int i = 0; i < 8; ++i)
#pragma unroll
    for (int j = 0; j < 2; ++j)
#pragma unroll
      for (int r = 0; r < 4; ++r) zt += exp2f(sfr[i][j][r] - mt);

#pragma unroll
  for (int off = 1; off < 64; off <<= 1) {
    float m2 = __shfl_xor(mt, off);
    float z2 = __shfl_xor(zt, off);
    float M = fmaxf(mt, m2);
    zt = zt * exp2f(mt - M) + z2 * exp2f(m2 - M);
    mt = M;
  }
  if (lane == 0) { wm[w] = mt; wz[w] = zt; }
  __syncthreads();
  if (t == 0) {
    float m = wm[0], z = wz[0];
#pragma unroll
    for (int i = 1; i < 4; ++i) {
      float M = fmaxf(m, wm[i]);
      z = z * exp2f(m - M) + wz[i] * exp2f(wm[i] - M);
      m = M;
    }
    int idx = (b * 32 + ny) * 32 + mx;
    pm[idx] = m; ps[idx] = z;
  }
}

// ---------------------------------------------------------------------------
// Kernel 3: combine partials -> C'_b = M' + log2(Z')
// ---------------------------------------------------------------------------
__global__ __launch_bounds__(256) void reduce_kernel(char* __restrict__ wsb)
{
  const int b = blockIdx.x;
  const float* pm = (const float*)(wsb + PM_B) + (size_t)b * 1024;
  const float* ps = (const float*)(wsb + PS_B) + (size_t)b * 1024;
  const int t = threadIdx.x;
  float m = -1e30f, z = 0.f;
  for (int i = t; i < 1024; i += 256) {
    float m2 = pm[i], z2 = ps[i];
    float M = fmaxf(m, m2);
    z = z * exp2f(m - M) + z2 * exp2f(m2 - M);
    m = M;
  }
#pragma unroll
  for (int off = 1; off < 64; off <<= 1) {
    float m2 = __shfl_xor(m, off);
    float z2 = __shfl_xor(z, off);
    float M = fmaxf(m, m2);
    z = z * exp2f(m - M) + z2 * exp2f(m2 - M);
    m = M;
  }
  __shared__ float wm[4], wz[4];
  int w = t >> 6;
  if ((t & 63) == 0) { wm[w] = m; wz[w] = z; }
  __syncthreads();
  if (t == 0) {
    float M = wm[0], Z = wz[0];
#pragma unroll
    for (int i = 1; i < 4; ++i) {
      float Mn = fmaxf(M, wm[i]);
      Z = Z * exp2f(M - Mn) + wz[i] * exp2f(wm[i] - Mn);
      M = Mn;
    }
    ((float*)(wsb + C_B))[b] = M + log2f(Z);
  }
}

// ---------------------------------------------------------------------------
// Kernel 4: attention output, n-split 2. Round-4 geometry: block = 256 o x
// 64 m, 8 waves (512 thr), chunk n=128, 16 chunks per block over its n-half.
// Grid 1024 = 8 b x 64 mt x 2 halves -> 3 blocks/CU (LDS 48KB).
// Frag-major LDS (all ops conflict-free):
//   qt_s frag u(=n>>4, 0..7): lane l = Q[n=u*16+l16][d=l4*8..+7]
//   as_s frag f=kk*4+mf:      lane l = P^T[m=mf*16+l16][n=kk*32+l4*8..+7]
// half 0 -> bf16 partial to ws; half 1 -> raw f32 acc to out.
// ---------------------------------------------------------------------------
__global__ __launch_bounds__(512, 4) void attn_out(
    char* __restrict__ wsb, float* __restrict__ out)
{
  __shared__ alignas(16) char qt_s[2][8192];   // 8 frags x 1KB, dbuf
  __shared__ alignas(16) char as_s[2][16384];  // 16 frags x 1KB, dbuf
  const int bid = blockIdx.x;
  const int b = bid & 7;
  const int rest = bid >> 3;
  const int mt = rest & 63;
  const int half = rest >> 6;
  const int m0 = mt * 64;
  const int nbase = half * 2048;
  const int t = threadIdx.x, w = t >> 6, lane = t & 63;
  const int l4 = lane >> 4, l16 = lane & 15;
  const ushort* vb  = (const ushort*)(wsb + VB_B) + (size_t)b * NC * SN;
  const ushort* qtb = (const ushort*)(wsb + QT_B) + (size_t)b * SN * ND;
  const ushort* ktb = (const ushort*)(wsb + KT_B) + (size_t)b * SN * ND;
  const float Cb = ((const float*)(wsb + C_B))[b];

  // S-phase role: wave -> (m-frag 0..3, n-half-of-chunk 0..1)
  const int mfS = w & 3;
  const int nh  = w >> 2;
  const int mS_l = mfS * 16 + l16;
  short8 bfr = *(const short8*)(ktb + (size_t)(m0 + mS_l) * ND + l4 * 8);

  // as_s frag-major write base (derived: f=(nf>>1)*4+mfS, lane'=((nf*2+l4h)&3)*16+l16)
  const int as_wb = mfS * 1024 + l16 * 16 + (l4 & 1) * 8;
  const int l4h = l4 >> 1;

  // qt_s frag-major staging: thread (qrow,qsl): frag qrow>>4, lane qsl*16+(qrow&15)
  const int qrow = t >> 2, qsl = t & 3;
  const int qt_addr = (qrow >> 4) * 1024 + ((qsl * 16 + (qrow & 15)) << 4);

  // PV: wave owns o-slice [w*32, w*32+32)
  const ushort* vrow0 = vb + (size_t)(w * 32 + l16) * SN + nbase + l4 * 8;
  const ushort* vrow1 = vrow0 + (size_t)16 * SN;

  const f32x4 zf = {0.f, 0.f, 0.f, 0.f};
  f32x4 acc[2][4] = {};

  // prologue: stage qt chunk 0 of this half
  *(uint4*)(qt_s[0] + qt_addr) = *(const uint4*)(qtb + (size_t)(nbase + qrow) * ND + qsl * 8);
  __syncthreads();

  for (int i = 0; i < 16; ++i) {
    const int cur = i & 1;
    // V loads for this chunk (drained by the barrier; consumed in PV)
    short8 vf[2][4];
#pragma unroll
    for (int kk = 0; kk < 4; ++kk) {
      vf[0][kk] = *(const short8*)(vrow0 + i * 128 + kk * 32);
      vf[1][kk] = *(const short8*)(vrow1 + i * 128 + kk * 32);
    }
    // q^T prefetch for next chunk
    uint4 qnext;
    const bool pf = (i < 15);
    if (pf) qnext = *(const uint4*)(qtb + (size_t)(nbase + (i + 1) * 128 + qrow) * ND + qsl * 8);

    // S phase: 4 conflict-free frag reads, MFMA, exp2, frag-major write
#pragma unroll
    for (int ii = 0; ii < 4; ++ii) {
      int nf = nh * 4 + ii;
      short8 af = *(const short8*)(qt_s[cur] + nf * 1024 + lane * 16);
      f32x4 sv = __builtin_amdgcn_mfma_f32_16x16x32_bf16(af, bfr, zf, 0, 0, 0);
      uint2 pk;
      pk.x = bfpack2(exp2f(sv[0] - Cb), exp2f(sv[1] - Cb));
      pk.y = bfpack2(exp2f(sv[2] - Cb), exp2f(sv[3] - Cb));
      int addr = (nf >> 1) * 4096 + ((nf * 2 + l4h) & 3) * 256 + as_wb;
      *(uint2*)(as_s[cur] + addr) = pk;
    }
    if (pf)
      *(uint4*)(qt_s[cur ^ 1] + qt_addr) = qnext;
    __syncthreads();

    // PV phase: conflict-free frag-major reads + MFMA cluster
    __builtin_amdgcn_s_setprio(1);
#pragma unroll
    for (int kk = 0; kk < 4; ++kk) {
#pragma unroll
      for (int mf = 0; mf < 4; ++mf) {
        short8 paf = *(const short8*)(as_s[cur] + (kk * 4 + mf) * 1024 + lane * 16);
        acc[0][mf] = __builtin_amdgcn_mfma_f32_16x16x32_bf16(vf[0][kk], paf, acc[0][mf], 0, 0, 0);
        acc[1][mf] = __builtin_amdgcn_mfma_f32_16x16x32_bf16(vf[1][kk], paf, acc[1][mf], 0, 0, 0);
      }
    }
    __builtin_amdgcn_s_setprio(0);
  }

  // epilogue: half 0 -> bf16 partial buffer; half 1 -> raw f32 to out
  if (half == 0) {
    ushort* pb = (ushort*)(wsb + PB_B);
#pragma unroll
    for (int of = 0; of < 2; ++of)
#pragma unroll
      for (int mf = 0; mf < 4; ++mf) {
        int m = m0 + mf * 16 + l16;
#pragma unroll
        for (int j = 0; j < 4; ++j) {
          int o = w * 32 + of * 16 + l4 * 4 + j;
          pb[((size_t)b * NC + o) * SN + m] = (ushort)bf16rne(acc[of][mf][j]);
        }
      }
  } else {
#pragma unroll
    for (int of = 0; of < 2; ++of)
#pragma unroll
      for (int mf = 0; mf < 4; ++mf) {
        int m = m0 + mf * 16 + l16;
#pragma unroll
        for (int j = 0; j < 4; ++j) {
          int o = w * 32 + of * 16 + l4 * 4 + j;
          out[((size_t)b * NC + o) * SN + m] = acc[of][mf][j];
        }
      }
  }
}

// ---------------------------------------------------------------------------
// Kernel 5: combine halves + skip: out = out + bf16(PB) + x
// ---------------------------------------------------------------------------
__global__ __launch_bounds__(256) void combine_kernel(
    const char* __restrict__ wsb, const float* __restrict__ x, float* __restrict__ out)
{
  const ushort* pb = (const ushort*)(wsb + PB_B);
  const size_t total = (size_t)NBATCH * NC * SN;
  for (size_t i = ((size_t)blockIdx.x * 256 + threadIdx.x) * 4; i < total;
       i += (size_t)gridDim.x * 256 * 4) {
    float4 o = *(const float4*)(out + i);
    ushort4 p = *(const ushort4*)(pb + i);
    float4 xx = *(const float4*)(x + i);
    o.x += __uint_as_float((unsigned)p.x << 16) + xx.x;
    o.y += __uint_as_float((unsigned)p.y << 16) + xx.y;
    o.z += __uint_as_float((unsigned)p.z << 16) + xx.z;
    o.w += __uint_as_float((unsigned)p.w << 16) + xx.w;
    *(float4*)(out + i) = o;
  }
}

extern "C" void kernel_launch(void* const* d_in, const int* in_sizes, int n_in,
                              void* d_out, int out_size, void* d_ws, size_t ws_size,
                              hipStream_t stream)
{
  const float* x  = (const float*)d_in[0];
  const float* W1 = (const float*)d_in[1];
  const float* b1 = (const float*)d_in[2];
  const float* W2 = (const float*)d_in[3];
  const float* b2 = (const float*)d_in[4];
  const float* W3 = (const float*)d_in[5];
  const float* b3 = (const float*)d_in[6];
  char* wsb  = (char*)d_ws;
  float* out = (float*)d_out;

  prep_kernel<<<80, 256, 0, stream>>>(W1, b1, W2, b2, W3, b3, wsb);
  proj_kernel<<<256, 512, 0, stream>>>(x, wsb);
  qk_stats<<<8192, 256, 0, stream>>>(wsb, (float*)(wsb + PM_B), (float*)(wsb + PS_B));
  reduce_kernel<<<NBATCH, 256, 0, stream>>>(wsb);
  attn_out<<<1024, 512, 0, stream>>>(wsb, out);
  combine_kernel<<<2048, 256, 0, stream>>>(wsb, x, out);
}

// Round 10
// 211.828 us; speedup vs baseline: 1.7350x; 1.0600x over previous
//
#include <hip/hip_runtime.h>
#include <hip/hip_bf16.h>
#include <math.h>

#define NBATCH 8
#define NC 256
#define ND 32
#define SN 4096

// Workspace byte offsets
constexpr size_t VB_B   = 0;                      // 16 MB bf16 V [b][o][n]
constexpr size_t QT_B   = 16777216;               // 2 MB bf16 Q^T [b][n][d] (pre-scaled by log2e)
constexpr size_t KT_B   = QT_B + 2097152;         // 2 MB bf16 K^T [b][m][d]
constexpr size_t PM_B   = KT_B + 2097152;         // partial max (exp2 domain)
constexpr size_t PS_B   = PM_B + 32768;           // partial sum2
constexpr size_t C_B    = PS_B + 32768;           // 8 f32: C' = M' + log2(Z')
constexpr size_t WB_B   = C_B + 64;               // 320*256 bf16 packed weights
constexpr size_t BIAS_B = WB_B + 163840;          // 320 f32 biases

typedef __attribute__((ext_vector_type(8))) short short8;
typedef __attribute__((ext_vector_type(4))) float f32x4;

__device__ __forceinline__ unsigned bf16rne(float f) {
  unsigned u = __float_as_uint(f);
  return (u + 0x7fffu + ((u >> 16) & 1u)) >> 16;
}
__device__ __forceinline__ unsigned bfpack2(float lo, float hi) {
  union { __hip_bfloat162 h; unsigned u; } cv;
  cv.h.x = __float2bfloat16(lo);
  cv.h.y = __float2bfloat16(hi);
  return cv.u;
}

// ---------------------------------------------------------------------------
// Kernel 0: pack W1|W2*log2e|W3 -> bf16 Wb[320][256], biases -> f32[320]
// ---------------------------------------------------------------------------
__global__ __launch_bounds__(256) void prep_kernel(
    const float* __restrict__ W1, const float* __restrict__ b1,
    const float* __restrict__ W2, const float* __restrict__ b2,
    const float* __restrict__ W3, const float* __restrict__ b3,
    char* __restrict__ wsb)
{
  ushort* Wb = (ushort*)(wsb + WB_B);
  float* bias = (float*)(wsb + BIAS_B);
  const float LOG2E = 1.4426950408889634f;
  int idx = blockIdx.x * 256 + threadIdx.x;
  int r = idx >> 6, c4 = (idx & 63) * 4;
  float4 v; float sc = 1.0f;
  if (r < 256)      { v = *(const float4*)(W1 + (size_t)r * 256 + c4); }
  else if (r < 288) { v = *(const float4*)(W2 + (size_t)(r - 256) * 256 + c4); sc = LOG2E; }
  else              { v = *(const float4*)(W3 + (size_t)(r - 288) * 256 + c4); }
  ushort4 o;
  o.x = (ushort)bf16rne(v.x * sc); o.y = (ushort)bf16rne(v.y * sc);
  o.z = (ushort)bf16rne(v.z * sc); o.w = (ushort)bf16rne(v.w * sc);
  *(ushort4*)(Wb + (size_t)r * 256 + c4) = o;
  if (blockIdx.x == 0 && threadIdx.x < 320) {
    int q = threadIdx.x;
    bias[q] = q < 256 ? b1[q] : (q < 288 ? b2[q - 256] * LOG2E : b3[q - 288]);
  }
}

// ---------------------------------------------------------------------------
// Kernel 1: MFMA projections (unchanged)
// ---------------------------------------------------------------------------
__global__ __launch_bounds__(512) void proj_kernel(
    const float* __restrict__ x, char* __restrict__ wsb)
{
  __shared__ alignas(16) char xT[65536];    // [128 n][256 c] bf16, swz ((n&7)<<4)
  __shared__ alignas(16) char Wsh[40960];   // [320 o][64 c] bf16 chunk, swz ((o&7)<<4)
  const int bid = blockIdx.x;
  const int b = bid & 7, nt = bid >> 3;
  const int n0 = nt * 128;
  const int t = threadIdx.x, w = t >> 6, lane = t & 63;
  const int l4 = lane >> 4, l16 = lane & 15;
  const float* xb = x + (size_t)b * NC * SN;
  const ushort* Wb = (const ushort*)(wsb + WB_B);
  const float* bias = (const float*)(wsb + BIAS_B);
  ushort* vbuf  = (ushort*)(wsb + VB_B);
  ushort* qtbuf = (ushort*)(wsb + QT_B);
  ushort* ktbuf = (ushort*)(wsb + KT_B);

  {
    int cp = w * 16 + l16;
    int c  = cp * 2;
    int nb0 = l4 * 4;
#pragma unroll
    for (int ni = 0; ni < 8; ++ni) {
      int nB = ni * 16 + nb0;
      float4 a0 = *(const float4*)(xb + (size_t)c * SN + n0 + nB);
      float4 a1 = *(const float4*)(xb + (size_t)(c + 1) * SN + n0 + nB);
      const float* p0 = (const float*)&a0;
      const float* p1 = (const float*)&a1;
#pragma unroll
      for (int j = 0; j < 4; ++j) {
        int n = nB + j;
        *(uint*)(xT + n * 512 + ((cp * 4) ^ ((n & 7) << 4))) = bfpack2(p0[j], p1[j]);
      }
    }
  }
#pragma unroll
  for (int ii = 0; ii < 5; ++ii) {
    int slot = t + ii * 512;
    int r = slot >> 3, cc = slot & 7;
    *(uint4*)(Wsh + r * 128 + ((cc * 16) ^ ((r & 7) << 4))) =
        *(const uint4*)(Wb + (size_t)r * 256 + cc * 8);
  }
  __syncthreads();

  const int of_g = w >> 1;
  const int nf_g = w & 1;
  f32x4 acc[5][4] = {};

  for (int c4 = 0; c4 < 4; ++c4) {
#pragma unroll
    for (int kk = 0; kk < 2; ++kk) {
      short8 a[4];
#pragma unroll
      for (int nf = 0; nf < 4; ++nf) {
        int n = nf_g * 64 + nf * 16 + l16;
        a[nf] = *(const short8*)(xT + n * 512 +
                 ((c4 * 128 + kk * 64 + l4 * 16) ^ ((n & 7) << 4)));
      }
#pragma unroll
      for (int of = 0; of < 5; ++of) {
        int o = (of_g * 5 + of) * 16 + l16;
        short8 bf = *(const short8*)(Wsh + o * 128 +
                    ((kk * 64 + l4 * 16) ^ ((o & 7) << 4)));
#pragma unroll
        for (int nf = 0; nf < 4; ++nf)
          acc[of][nf] = __builtin_amdgcn_mfma_f32_16x16x32_bf16(a[nf], bf, acc[of][nf], 0, 0, 0);
      }
    }
    if (c4 < 3) {
      __syncthreads();
#pragma unroll
      for (int ii = 0; ii < 5; ++ii) {
        int slot = t + ii * 512;
        int r = slot >> 3, cc = slot & 7;
        *(uint4*)(Wsh + r * 128 + ((cc * 16) ^ ((r & 7) << 4))) =
            *(const uint4*)(Wb + (size_t)r * 256 + (c4 + 1) * 64 + cc * 8);
      }
      __syncthreads();
    }
  }

#pragma unroll
  for (int of = 0; of < 5; ++of) {
    int o = (of_g * 5 + of) * 16 + l16;
    float bv = bias[o];
#pragma unroll
    for (int nf = 0; nf < 4; ++nf) {
      int nb = nf_g * 64 + nf * 16 + l4 * 4;
      float v0 = acc[of][nf][0] + bv, v1 = acc[of][nf][1] + bv;
      float v2 = acc[of][nf][2] + bv, v3 = acc[of][nf][3] + bv;
      if (o < 256) {
        uint2 pk; pk.x = bfpack2(v0, v1); pk.y = bfpack2(v2, v3);
        *(uint2*)(vbuf + ((size_t)b * NC + o) * SN + n0 + nb) = pk;
      } else if (o < 288) {
        int d = o - 256;
        qtbuf[((size_t)b * SN + n0 + nb + 0) * ND + d] = (ushort)bf16rne(v0);
        qtbuf[((size_t)b * SN + n0 + nb + 1) * ND + d] = (ushort)bf16rne(v1);
        qtbuf[((size_t)b * SN + n0 + nb + 2) * ND + d] = (ushort)bf16rne(v2);
        qtbuf[((size_t)b * SN + n0 + nb + 3) * ND + d] = (ushort)bf16rne(v3);
      } else {
        int d = o - 288;
        ktbuf[((size_t)b * SN + n0 + nb + 0) * ND + d] = (ushort)bf16rne(v0);
        ktbuf[((size_t)b * SN + n0 + nb + 1) * ND + d] = (ushort)bf16rne(v1);
        ktbuf[((size_t)b * SN + n0 + nb + 2) * ND + d] = (ushort)bf16rne(v2);
        ktbuf[((size_t)b * SN + n0 + nb + 3) * ND + d] = (ushort)bf16rne(v3);
      }
    }
  }
}

// ---------------------------------------------------------------------------
// Kernel 2: QK^T tile stats in exp2 domain (unchanged)
// ---------------------------------------------------------------------------
__global__ __launch_bounds__(256) void qk_stats(
    const char* __restrict__ wsb, float* __restrict__ pm, float* __restrict__ ps)
{
  __shared__ alignas(16) char qt_s[128 * 64];
  __shared__ alignas(16) char kt_s[128 * 64];
  __shared__ float wm[4], wz[4];
  const int bid = blockIdx.x;
  const int b = bid & 7, ny = (bid >> 3) & 31, mx = bid >> 8;
  const int n0 = ny * 128, m0 = mx * 128;
  const int t = threadIdx.x, w = t >> 6, lane = t & 63;
  const int l4 = lane >> 4, l16 = lane & 15;
  const ushort* qtb = (const ushort*)(wsb + QT_B) + (size_t)b * SN * ND;
  const ushort* ktb = (const ushort*)(wsb + KT_B) + (size_t)b * SN * ND;
  {
    int row = t >> 1, db = (t & 1) * 32;
#pragma unroll
    for (int i = 0; i < 2; ++i) {
      int b16 = db + i * 16;
      int dst = row * 64 + (b16 ^ ((row & 3) << 4));
      *(uint4*)(qt_s + dst) = *(const uint4*)(qtb + (size_t)(n0 + row) * ND + b16 / 2);
      *(uint4*)(kt_s + dst) = *(const uint4*)(ktb + (size_t)(m0 + row) * ND + b16 / 2);
    }
  }
  __syncthreads();
  const f32x4 zf = {0.f, 0.f, 0.f, 0.f};
  short8 bfr[2];
#pragma unroll
  for (int j = 0; j < 2; ++j) {
    int mm = (w * 2 + j) * 16 + l16;
    bfr[j] = *(const short8*)(kt_s + mm * 64 + ((l4 * 16) ^ ((mm & 3) << 4)));
  }
  f32x4 sfr[8][2];
#pragma unroll
  for (int i = 0; i < 8; ++i) {
    int nn = i * 16 + l16;
    short8 af = *(const short8*)(qt_s + nn * 64 + ((l4 * 16) ^ ((nn & 3) << 4)));
#pragma unroll
    for (int j = 0; j < 2; ++j)
      sfr[i][j] = __builtin_amdgcn_mfma_f32_16x16x32_bf16(af, bfr[j], zf, 0, 0, 0);
  }
  float mt = -1e30f;
#pragma unroll
  for (int i = 0; i < 8; ++i)
#pragma unroll
    for (int j = 0; j < 2; ++j)
#pragma unroll
      for (int r = 0; r < 4; ++r) mt = fmaxf(mt, sfr[i][j][r]);
  float zt = 0.f;
#pragma unroll
  for (int i = 0; i < 8; ++i)
#pragma unroll
    for (int j = 0; j < 2; ++j)
#pragma unroll
      for (int r = 0; r < 4; ++r) zt += exp2f(sfr[i][j][r] - mt);

#pragma unroll
  for (int off = 1; off < 64; off <<= 1) {
    float m2 = __shfl_xor(mt, off);
    float z2 = __shfl_xor(zt, off);
    float M = fmaxf(mt, m2);
    zt = zt * exp2f(mt - M) + z2 * exp2f(m2 - M);
    mt = M;
  }
  if (lane == 0) { wm[w] = mt; wz[w] = zt; }
  __syncthreads();
  if (t == 0) {
    float m = wm[0], z = wz[0];
#pragma unroll
    for (int i = 1; i < 4; ++i) {
      float M = fmaxf(m, wm[i]);
      z = z * exp2f(m - M) + wz[i] * exp2f(wm[i] - M);
      m = M;
    }
    int idx = (b * 32 + ny) * 32 + mx;
    pm[idx] = m; ps[idx] = z;
  }
}

// ---------------------------------------------------------------------------
// Kernel 3: combine partials -> C'_b = M' + log2(Z')
// ---------------------------------------------------------------------------
__global__ __launch_bounds__(256) void reduce_kernel(char* __restrict__ wsb)
{
  const int b = blockIdx.x;
  const float* pm = (const float*)(wsb + PM_B) + (size_t)b * 1024;
  const float* ps = (const float*)(wsb + PS_B) + (size_t)b * 1024;
  const int t = threadIdx.x;
  float m = -1e30f, z = 0.f;
  for (int i = t; i < 1024; i += 256) {
    float m2 = pm[i], z2 = ps[i];
    float M = fmaxf(m, m2);
    z = z * exp2f(m - M) + z2 * exp2f(m2 - M);
    m = M;
  }
#pragma unroll
  for (int off = 1; off < 64; off <<= 1) {
    float m2 = __shfl_xor(m, off);
    float z2 = __shfl_xor(z, off);
    float M = fmaxf(m, m2);
    z = z * exp2f(m - M) + z2 * exp2f(m2 - M);
    m = M;
  }
  __shared__ float wm[4], wz[4];
  int w = t >> 6;
  if ((t & 63) == 0) { wm[w] = m; wz[w] = z; }
  __syncthreads();
  if (t == 0) {
    float M = wm[0], Z = wz[0];
#pragma unroll
    for (int i = 1; i < 4; ++i) {
      float Mn = fmaxf(M, wm[i]);
      Z = Z * exp2f(M - Mn) + wz[i] * exp2f(wm[i] - Mn);
      M = Mn;
    }
    ((float*)(wsb + C_B))[b] = M + log2f(Z);
  }
}

// ---------------------------------------------------------------------------
// Kernel 4: attention output. 4-wave block = 128 o x 64 m, chunk n=64,
// grid 1024 (8 b x 64 mt x 2 o-halves) -> 4 independent barrier-groups / CU.
// Frag-major LDS (all frag reads lane*16B contiguous):
//   qt_s frag u (0..3):        lane l = Q[n=u*16+(l&15)][d=(l>>4)*8..+7]
//   as_s frag f=kk*4+mf (0..7): lane l = P^T[m=mf*16+(l&15)][n=kk*32+(l>>4)*8..+7]
// Wave w: S for m-frag w over all 4 n-frags (writes frags {w, w+4});
//         PV for o-slice [oh*128 + w*32, +32) x all 64 m.
// ---------------------------------------------------------------------------
__global__ __launch_bounds__(256) void attn_out(
    const char* __restrict__ wsb, const float* __restrict__ x, float* __restrict__ out)
{
  __shared__ alignas(16) char qt_s[2][4096];   // 4 frags x 1KB, dbuf
  __shared__ alignas(16) char as_s[2][8192];   // 8 frags x 1KB, dbuf
  const int bid = blockIdx.x;
  const int b = bid & 7;
  const int rest = bid >> 3;
  const int mt = rest & 63;
  const int oh = rest >> 6;                    // o-half 0/1
  const int m0 = mt * 64;
  const int o0 = oh * 128;
  const int t = threadIdx.x, w = t >> 6, lane = t & 63;
  const int l4 = lane >> 4, l16 = lane & 15;
  const ushort* vb  = (const ushort*)(wsb + VB_B) + (size_t)b * NC * SN;
  const ushort* qtb = (const ushort*)(wsb + QT_B) + (size_t)b * SN * ND;
  const ushort* ktb = (const ushort*)(wsb + KT_B) + (size_t)b * SN * ND;
  const float Cb = ((const float*)(wsb + C_B))[b];

  // S role: this wave owns m-frag w
  const int mS_l = w * 16 + l16;
  short8 bfr = *(const short8*)(ktb + (size_t)(m0 + mS_l) * ND + l4 * 8);

  // as_s frag-major write base (same verified mapping as round 9, mfS = w)
  const int as_wb = w * 1024 + l16 * 16 + (l4 & 1) * 8;
  const int l4h = l4 >> 1;

  // qt staging: thread -> (qrow = t>>2, qsl = t&3); wave w stages frag w
  const int qrow = t >> 2, qsl = t & 3;
  const int qt_addr = (qrow >> 4) * 1024 + ((qsl * 16 + (qrow & 15)) << 4);

  // PV: wave owns o-slice [o0 + w*32, +32)
  const ushort* vrow0 = vb + (size_t)(o0 + w * 32 + l16) * SN + l4 * 8;
  const ushort* vrow1 = vrow0 + (size_t)16 * SN;

  const f32x4 zf = {0.f, 0.f, 0.f, 0.f};
  f32x4 acc[2][4] = {};

  // prologue: stage qt chunk 0
  *(uint4*)(qt_s[0] + qt_addr) = *(const uint4*)(qtb + (size_t)qrow * ND + qsl * 8);
  __syncthreads();

  for (int i = 0; i < 64; ++i) {
    const int cur = i & 1;
    // V loads for this chunk (consumed after the barrier)
    short8 vf[2][2];
#pragma unroll
    for (int kk = 0; kk < 2; ++kk) {
      vf[0][kk] = *(const short8*)(vrow0 + i * 64 + kk * 32);
      vf[1][kk] = *(const short8*)(vrow1 + i * 64 + kk * 32);
    }
    // q^T prefetch for next chunk
    uint4 qnext;
    const bool pf = (i < 63);
    if (pf) qnext = *(const uint4*)(qtb + (size_t)((i + 1) * 64 + qrow) * ND + qsl * 8);

    // S phase: 4 n-frags for this wave's m-frag
#pragma unroll
    for (int nf = 0; nf < 4; ++nf) {
      short8 af = *(const short8*)(qt_s[cur] + nf * 1024 + lane * 16);
      f32x4 sv = __builtin_amdgcn_mfma_f32_16x16x32_bf16(af, bfr, zf, 0, 0, 0);
      uint2 pk;
      pk.x = bfpack2(exp2f(sv[0] - Cb), exp2f(sv[1] - Cb));
      pk.y = bfpack2(exp2f(sv[2] - Cb), exp2f(sv[3] - Cb));
      int addr = (nf >> 1) * 4096 + (((nf & 1) * 2 + l4h) & 3) * 256 + as_wb;
      *(uint2*)(as_s[cur] + addr) = pk;
    }
    if (pf)
      *(uint4*)(qt_s[cur ^ 1] + qt_addr) = qnext;
    __syncthreads();

    // PV phase: 16 MFMAs, frag-major reads
    __builtin_amdgcn_s_setprio(1);
#pragma unroll
    for (int kk = 0; kk < 2; ++kk) {
#pragma unroll
      for (int mf = 0; mf < 4; ++mf) {
        short8 paf = *(const short8*)(as_s[cur] + (kk * 4 + mf) * 1024 + lane * 16);
        acc[0][mf] = __builtin_amdgcn_mfma_f32_16x16x32_bf16(vf[0][kk], paf, acc[0][mf], 0, 0, 0);
        acc[1][mf] = __builtin_amdgcn_mfma_f32_16x16x32_bf16(vf[1][kk], paf, acc[1][mf], 0, 0, 0);
      }
    }
    __builtin_amdgcn_s_setprio(0);
  }

  // epilogue: out = acc + x
#pragma unroll
  for (int of = 0; of < 2; ++of)
#pragma unroll
    for (int mf = 0; mf < 4; ++mf) {
      int m = m0 + mf * 16 + l16;
#pragma unroll
      for (int j = 0; j < 4; ++j) {
        int o = o0 + w * 32 + of * 16 + l4 * 4 + j;
        size_t idx = ((size_t)b * NC + o) * SN + m;
        out[idx] = acc[of][mf][j] + x[idx];
      }
    }
}

extern "C" void kernel_launch(void* const* d_in, const int* in_sizes, int n_in,
                              void* d_out, int out_size, void* d_ws, size_t ws_size,
                              hipStream_t stream)
{
  const float* x  = (const float*)d_in[0];
  const float* W1 = (const float*)d_in[1];
  const float* b1 = (const float*)d_in[2];
  const float* W2 = (const float*)d_in[3];
  const float* b2 = (const float*)d_in[4];
  const float* W3 = (const float*)d_in[5];
  const float* b3 = (const float*)d_in[6];
  char* wsb  = (char*)d_ws;
  float* out = (float*)d_out;

  prep_kernel<<<80, 256, 0, stream>>>(W1, b1, W2, b2, W3, b3, wsb);
  proj_kernel<<<256, 512, 0, stream>>>(x, wsb);
  qk_stats<<<8192, 256, 0, stream>>>(wsb, (float*)(wsb + PM_B), (float*)(wsb + PS_B));
  reduce_kernel<<<NBATCH, 256, 0, stream>>>(wsb);
  attn_out<<<1024, 256, 0, stream>>>(wsb, x, out);
}